// Round 11
// baseline (264.293 us; speedup 1.0000x reference)
//
#include <hip/hip_runtime.h>
#include <hip/hip_bf16.h>

typedef short short8 __attribute__((ext_vector_type(8)));
typedef short short4v __attribute__((ext_vector_type(4)));
typedef float floatx4 __attribute__((ext_vector_type(4)));
typedef float floatx4v __attribute__((ext_vector_type(4)));

#define SCALE_F 0.10206207261596575f

static __device__ __forceinline__ float b2f(unsigned short u){
  unsigned int v = ((unsigned int)u) << 16; float f;
  __builtin_memcpy(&f, &v, 4); return f;
}
static __device__ __forceinline__ unsigned short f2b(float f){
  __hip_bfloat16 h = __float2bfloat16(f);
  unsigned short u; __builtin_memcpy(&u, &h, 2); return u;
}
static __device__ __forceinline__ int map20(int i){
  return (i < 2) ? i : 7 + ((i-2)/3)*8 + ((i-2)%3);
}

struct ConvDesc {
  const void* src[17];
  long long off[17];
  int count[17];
};

// ---------------- K0: dtype detect + convert SMALL tensors (1..16) to bf16 ------------
__global__ __launch_bounds__(256) void k_convert(ConvDesc d, unsigned short* dst_base,
                                                 int* flagp, const unsigned int* xprobe)
{
  __shared__ int sflag;
  if (threadIdx.x < 64){
    unsigned int w = xprobe[1024 + threadIdx.x];
    int e = (w >> 7) & 0xFF;
    int pl = (e >= 90 && e <= 140) ? 1 : 0;
    unsigned long long m = __ballot(pl);
    if (threadIdx.x == 0){
      sflag = (__popcll(m) < 40) ? 1 : 0;   // 1 = inputs are fp32
      if (blockIdx.x == 0 && blockIdx.y == 0) *flagp = sflag;
    }
  }
  __syncthreads();
  const int flag = sflag;
  const int t = blockIdx.y + 1;             // skip x (tensor 0)
  const int cnt = d.count[t];
  unsigned short* dst = dst_base + d.off[t];
  const float* sf = (const float*)d.src[t];
  const unsigned short* su = (const unsigned short*)d.src[t];
  for (int i = blockIdx.x*blockDim.x + threadIdx.x; i < cnt; i += gridDim.x*blockDim.x){
    dst[i] = flag ? f2b(sf[i]) : su[i];
  }
}

// load one 16-row A-fragment triple from x (flag-dependent dtype)
static __device__ __forceinline__ void load_x_frag(
    const void* xr_, int flag, size_t elem_off, short8& a0, short8& a1, short8& a2)
{
  if (flag){
    const float* xr = (const float*)xr_ + elem_off;
    floatx4v f0 = *(const floatx4v*)(xr),      f1 = *(const floatx4v*)(xr+4);
    floatx4v f2 = *(const floatx4v*)(xr+32),   f3 = *(const floatx4v*)(xr+36);
    floatx4v f4 = *(const floatx4v*)(xr+64),   f5 = *(const floatx4v*)(xr+68);
    #pragma unroll
    for (int j = 0; j < 4; ++j){
      a0[j] = (short)f2b(f0[j]); a0[j+4] = (short)f2b(f1[j]);
      a1[j] = (short)f2b(f2[j]); a1[j+4] = (short)f2b(f3[j]);
      a2[j] = (short)f2b(f4[j]); a2[j+4] = (short)f2b(f5[j]);
    }
  } else {
    const unsigned short* xr = (const unsigned short*)xr_ + elem_off;
    a0 = *(const short8*)(xr);
    a1 = *(const short8*)(xr + 32);
    a2 = *(const short8*)(xr + 64);
  }
}

// ---------------- K1: merged QKV GEMM ----------------
// Q path writes q_raw in [bh][token][96] layout via an LDS transpose tile.
__global__ __launch_bounds__(256) void k_qkv(
    const void* __restrict__ x, const unsigned short* __restrict__ w,
    const unsigned short* __restrict__ bias, unsigned short* __restrict__ qr,
    unsigned short* __restrict__ kc, unsigned short* __restrict__ vc,
    unsigned short* __restrict__ kcls, unsigned short* __restrict__ vcls,
    const int* __restrict__ flagp)
{
  __shared__ __align__(16) unsigned short T[64*200];   // 25.6 KB (Q path only)
  const int flag = *flagp;
  const int tid = threadIdx.x;
  const int lane = tid & 63;
  const int wv = tid >> 6;
  const int kq = (lane >> 4) * 8;
  const int quad = lane >> 4;
  const int col_l = lane & 15;

  if (blockIdx.x < 1569){
    // ---- Q path ----
    const int m_base = blockIdx.x * 64;
    const int row_l = wv * 16;
    int ma = m_base + row_l + col_l; if (ma > 100355) ma = 100355;
    short8 a0, a1, a2;
    load_x_frag(x, flag, (size_t)ma*96 + kq, a0, a1, a2);

    #pragma unroll
    for (int ct = 0; ct < 12; ++ct){
      int col = ct*16 + col_l;
      const unsigned short* wrow = w + col*96 + kq;
      short8 b0 = *(const short8*)(wrow);
      short8 b1 = *(const short8*)(wrow + 32);
      short8 b2 = *(const short8*)(wrow + 64);
      float bv = b2f(bias[col]);
      floatx4 acc = {0.f,0.f,0.f,0.f};
      acc = __builtin_amdgcn_mfma_f32_16x16x32_bf16(a0, b0, acc, 0,0,0);
      acc = __builtin_amdgcn_mfma_f32_16x16x32_bf16(a1, b1, acc, 0,0,0);
      acc = __builtin_amdgcn_mfma_f32_16x16x32_bf16(a2, b2, acc, 0,0,0);
      #pragma unroll
      for (int r = 0; r < 4; ++r)
        T[(row_l + quad*4 + r)*200 + ct*16 + col_l] = f2b(acc[r] + bv);
    }
    __syncthreads();

    // coalesced write-out: 1536 short8 chunks, 6 per thread
    #pragma unroll
    for (int k = 0; k < 6; ++k){
      int c = tid + k*256;
      int row = c / 24;
      int off = c - row*24;
      int m = m_base + row;
      if (m < 100356){
        int bb2 = m / 25089;
        int ntok = m - bb2*25089;
        int col8 = off*8;                  // 0..184
        int head = (col8 >= 96) ? 1 : 0;
        int d = col8 - head*96;
        short8 v = *(const short8*)(T + row*200 + col8);
        *(short8*)(qr + ((size_t)(bb2*2 + head)*25089 + (size_t)ntok)*96 + d) = v;
      }
    }
  } else {
    // ---- KV path (unchanged) ----
    const int id = blockIdx.x - 1569;
    const int isv = id / 201;
    const int bx = id - isv*201;
    const int rbase = bx * 64 + wv * 16;

    int rhoA = rbase + col_l; if (rhoA > 12803) rhoA = 12803;
    int bA, nA;
    if (rhoA < 4){ bA = rhoA; nA = 0; }
    else {
      int rp = rhoA - 4;
      bA = rp / 3200; int rem = rp - bA*3200;
      int t = rem / 400; int s = rem - t*400;
      int ry = s / 20, rx = s - ry*20;
      nA = 1 + (t*56 + map20(ry))*56 + map20(rx);
    }
    short8 a0, a1, a2;
    load_x_frag(x, flag, ((size_t)bA*25089 + nA)*96 + kq, a0, a1, a2);

    int isCls[4], bI[4], baseI[4], valid[4];
    #pragma unroll
    for (int r = 0; r < 4; ++r){
      int rho = rbase + quad*4 + r;
      valid[r] = (rho < 12804);
      if (rho > 12803) rho = 12803;
      if (rho < 4){ isCls[r] = 1; bI[r] = rho; baseI[r] = 0; }
      else {
        int rp = rho - 4;
        int b = rp / 3200; int rem = rp - b*3200;
        int t = rem / 400; int s = rem - t*400;
        int ry = s / 20, rx = s - ry*20;
        isCls[r] = 0; bI[r] = b;
        baseI[r] = (((b*8 + t)*20 + ry)*20 + rx)*192;
      }
    }

    unsigned short* buf  = isv ? vc : kc;
    unsigned short* bufc = isv ? vcls : kcls;
    #pragma unroll
    for (int ct = 0; ct < 12; ++ct){
      const int col = 192 + (isv*12 + ct)*16 + col_l;
      const unsigned short* wrow = w + col*96 + kq;
      short8 b0 = *(const short8*)(wrow);
      short8 b1 = *(const short8*)(wrow + 32);
      short8 b2 = *(const short8*)(wrow + 64);
      float bv = b2f(bias[col]);
      floatx4 acc = {0.f,0.f,0.f,0.f};
      acc = __builtin_amdgcn_mfma_f32_16x16x32_bf16(a0, b0, acc, 0,0,0);
      acc = __builtin_amdgcn_mfma_f32_16x16x32_bf16(a1, b1, acc, 0,0,0);
      acc = __builtin_amdgcn_mfma_f32_16x16x32_bf16(a2, b2, acc, 0,0,0);
      const int head = ct / 6;
      const int dstat = (ct % 6) * 16;
      #pragma unroll
      for (int r = 0; r < 4; ++r){
        if (valid[r]){
          float o = acc[r] + bv;
          if (isCls[r]) bufc[(bI[r]*2 + head)*96 + dstat + col_l] = f2b(o);
          else          buf[baseI[r] + head*96 + dstat + col_l]   = f2b(o);
        }
      }
    }
  }
}

// ---------------- K2: merged pooling ------------------------------------------------
// Q-pool path: blocks 0..895, each computes TWO t-outputs (t=2g, 2g+1) so the 4
// needed t-slices replace the 6 of two separate blocks (1.5x read cut). Bijective
// XCD swizzle (rb%8)*112+rb/8 gives each XCD one bh's q_raw slice (L2-resident).
// KV-pool path: blocks 896.. (unchanged logic).
__global__ __launch_bounds__(384) void k_pool(
    const unsigned short* __restrict__ qr, const unsigned short* __restrict__ cwq,
    const unsigned short* __restrict__ gq, const unsigned short* __restrict__ btaq,
    unsigned short* __restrict__ qp,
    const unsigned short* __restrict__ kc, const unsigned short* __restrict__ vc,
    const unsigned short* __restrict__ kcls, const unsigned short* __restrict__ vcls,
    const unsigned short* __restrict__ cwk, const unsigned short* __restrict__ gk, const unsigned short* __restrict__ bk,
    const unsigned short* __restrict__ cwv, const unsigned short* __restrict__ gv, const unsigned short* __restrict__ bv,
    unsigned short* __restrict__ kp, unsigned short* __restrict__ vt)
{
  const int tid = threadIdx.x;
  if (blockIdx.x < 896){
    // ================= Q-pool path (t-paired) =================
    __shared__ float wlds[27*96];
    __shared__ float gls[96], bls[96];
    __shared__ float ls1[2][29*12], ls2[2][29*12];
    __shared__ float lmean[2][29], linvs[2][29];

    const int rb = blockIdx.x;
    const int lbid = (rb & 7)*112 + (rb >> 3);   // XCD-affinity swizzle (bijective)
    const int y   = lbid % 28;
    const int grp = lbid / 28;                   // 0..31
    const int bh  = grp >> 2;
    const int g   = grp & 3;
    const int t0  = g*2;
    const bool has_cls = (y == 0 && g == 0);

    for (int idx = tid; idx < 27*96; idx += 384){
      int tap = idx / 96, d = idx - tap*96;
      wlds[idx] = b2f(cwq[d*27 + tap]);
    }
    for (int idx = tid; idx < 96; idx += 384){
      gls[idx] = b2f(gq[idx]); bls[idx] = b2f(btaq[idx]);
    }
    __syncthreads();

    const int x = tid / 12, dg = tid - x*12;
    const unsigned short* qbh = qr + (size_t)bh*25089*96;
    float val[2][8] = {{0,0,0,0,0,0,0,0},{0,0,0,0,0,0,0,0}};

    if (x < 28){
      #pragma unroll
      for (int tt4 = 0; tt4 < 4; ++tt4){
        const int tt = t0 - 1 + tt4;
        if (tt < 0 || tt >= 8) continue;
        #pragma unroll
        for (int dy = 0; dy < 3; ++dy){
          int yy = 2*y + dy - 1; if (yy < 0 || yy >= 56) continue;
          #pragma unroll
          for (int dx = 0; dx < 3; ++dx){
            int xv = 2*x + dx - 1; if (xv < 0 || xv >= 56) continue;
            short8 v = *(const short8*)(qbh + (size_t)(1 + (tt*56 + yy)*56 + xv)*96 + dg*8);
            float fv[8];
            #pragma unroll
            for (int j = 0; j < 8; ++j) fv[j] = b2f((unsigned short)v[j]);
            if (tt4 < 3){                      // tap dt = tt4 for output t0
              const float* wr = wlds + ((tt4*3+dy)*3+dx)*96 + dg*8;
              #pragma unroll
              for (int j = 0; j < 8; ++j) val[0][j] += fv[j] * wr[j];
            }
            if (tt4 >= 1){                     // tap dt = tt4-1 for output t0+1
              const float* wr = wlds + (((tt4-1)*3+dy)*3+dx)*96 + dg*8;
              #pragma unroll
              for (int j = 0; j < 8; ++j) val[1][j] += fv[j] * wr[j];
            }
          }
        }
      }
      #pragma unroll
      for (int tp = 0; tp < 2; ++tp){
        float s1 = 0.f, s2 = 0.f;
        #pragma unroll
        for (int j = 0; j < 8; ++j){ s1 += val[tp][j]; s2 += val[tp][j]*val[tp][j]; }
        ls1[tp][x*12+dg] = s1; ls2[tp][x*12+dg] = s2;
      }
    } else if (has_cls && tid >= 348 && tid < 360){
      int cdg = tid - 348;
      short8 v = *(const short8*)(qbh + cdg*8);
      float s1 = 0.f, s2 = 0.f;
      #pragma unroll
      for (int j = 0; j < 8; ++j){ val[0][j] = b2f((unsigned short)v[j]); s1 += val[0][j]; s2 += val[0][j]*val[0][j]; }
      ls1[0][28*12+cdg] = s1; ls2[0][28*12+cdg] = s2;
    }
    __syncthreads();

    if (tid < 58){
      int tp = tid / 29, row = tid - tp*29;
      if (row < 28 || (row == 28 && tp == 0 && has_cls)){
        float s1 = 0.f, s2 = 0.f;
        #pragma unroll
        for (int k = 0; k < 12; ++k){ s1 += ls1[tp][row*12+k]; s2 += ls2[tp][row*12+k]; }
        float mean = s1 * (1.f/96.f);
        float var  = s2 * (1.f/96.f) - mean*mean;
        lmean[tp][row] = mean; linvs[tp][row] = rsqrtf(var + 1e-5f);
      }
    }
    __syncthreads();

    if (x < 28){
      #pragma unroll
      for (int tp = 0; tp < 2; ++tp){
        float mean = lmean[tp][x], inv = linvs[tp][x];
        int tok = 1 + ((t0 + tp)*28 + y)*28 + x;
        short8 o;
        #pragma unroll
        for (int j = 0; j < 8; ++j)
          o[j] = (short)f2b((val[tp][j] - mean)*inv*gls[dg*8+j] + bls[dg*8+j]);
        *(short8*)(qp + ((size_t)bh*6273 + tok)*96 + dg*8) = o;
      }
    } else if (has_cls && tid >= 348 && tid < 360){
      int cdg = tid - 348;
      float mean = lmean[0][28], inv = linvs[0][28];
      short8 o;
      #pragma unroll
      for (int j = 0; j < 8; ++j)
        o[j] = (short)f2b((val[0][j] - mean)*inv*gls[cdg*8+j] + bls[cdg*8+j]);
      *(short8*)(qp + (size_t)bh*6273*96 + cdg*8) = o;
    }
  } else {
    // ================= KV-pool path: 3 units of 128 threads =================
    __shared__ float r1[3][128], r2s[3][128];
    const int unit = tid >> 7;              // 0..2
    const int d = tid & 127;
    const int u = (blockIdx.x - 896)*3 + unit;
    const bool live = (u < 6656);
    int isv = 0, bh = 0, key = 0;
    if (live){
      isv = u / 3328; int rem = u - isv*3328;
      bh = rem / 416; key = rem - bh*416;
    }
    const bool pad = (key >= 393);
    const int b = bh >> 1, head = bh & 1;
    const unsigned short* buf  = isv ? vc : kc;
    const unsigned short* bufc = isv ? vcls : kcls;
    const unsigned short* cw = (isv == 0) ? cwk : cwv;
    const unsigned short* g  = (isv == 0) ? gk : gv;
    const unsigned short* bt = (isv == 0) ? bk : bv;

    float val = 0.f;
    if (live && !pad && d < 96){
      if (key == 0) val = b2f(bufc[bh*96 + d]);
      else {
        int s = key - 1; int t = s / 49; int r2 = s - t*49; int y = r2 / 7; int xx = r2 - y*7;
        const unsigned short* wr = cw + d*27;
        float sum = 0.f;
        #pragma unroll
        for (int dt = 0; dt < 3; ++dt){
          int tt = t + dt - 1; if (tt < 0 || tt >= 8) continue;
          #pragma unroll
          for (int dy = 0; dy < 3; ++dy){
            if (y == 0 && dy == 0) continue;
            int ry = (y == 0) ? (dy - 1) : 2 + 3*(y-1) + dy;
            #pragma unroll
            for (int dx = 0; dx < 3; ++dx){
              if (xx == 0 && dx == 0) continue;
              int rx = (xx == 0) ? (dx - 1) : 2 + 3*(xx-1) + dx;
              sum += b2f(buf[(((b*8 + tt)*20 + ry)*20 + rx)*192 + head*96 + d]) * b2f(wr[(dt*3+dy)*3+dx]);
            }
          }
        }
        val = sum;
      }
    }
    r1[unit][d]  = (d < 96) ? val : 0.f;
    r2s[unit][d] = (d < 96) ? val*val : 0.f;
    __syncthreads();
    for (int off = 64; off > 0; off >>= 1){
      if (d < off){ r1[unit][d] += r1[unit][d+off]; r2s[unit][d] += r2s[unit][d+off]; }
      __syncthreads();
    }
    if (live && d < 96){
      float mean = r1[unit][0] * (1.f/96.f);
      float var  = r2s[unit][0] * (1.f/96.f) - mean*mean;
      float inv = rsqrtf(var + 1e-5f);
      float o = pad ? 0.f : (val - mean)*inv*b2f(g[d]) + b2f(bt[d]);
      if (isv == 0) kp[((size_t)bh*416 + key)*96 + d] = f2b(o);
      else          vt[((size_t)bh*96 + d)*416 + key] = f2b(o);
    }
  }
}

// ---------------- K4: fused attention — 32 q rows/block (R2 proven version) ---------
#define PSTR 424
__global__ __launch_bounds__(256, 3) void k_attn(
    const unsigned short* __restrict__ qp, const unsigned short* __restrict__ kp,
    const unsigned short* __restrict__ vt,
    const unsigned short* __restrict__ rph, const unsigned short* __restrict__ rpw,
    const unsigned short* __restrict__ rpt,
    unsigned short* __restrict__ ao, const int q_off)
{
  __shared__ unsigned short P[32*PSTR];              // 27.1 KB
  __shared__ __align__(16) float rel[24*36 + 4];     // 3.5 KB, [slot][m], stride 36
  __shared__ float mx_sh[4][32], sum_sh[4][32];

  const int bh = blockIdx.y;
  const int bb = bh >> 1, head = bh & 1;
  const int tid = threadIdx.x;
  const int lane = tid & 63;
  const int wv = tid >> 6;                   // 0..3
  const int q0 = (q_off + blockIdx.x) * 32;

  const unsigned short* qbase = qp + (size_t)bh*6273*96;
  const unsigned short* kbase = kp + (size_t)bh*416*96;
  const unsigned short* vbase = vt + (size_t)bh*96*416;

  const int col = lane & 15;
  const int quad = lane >> 4;
  const int kq = quad * 8;

  // Q A-fragments for tile A (rows q0..+15) and tile B (rows q0+16..+31)
  short8 aF[2][3];
  #pragma unroll
  for (int tl = 0; tl < 2; ++tl){
    int qa = q0 + tl*16 + col; if (qa > 6272) qa = 6272;
    const unsigned short* qrow = qbase + (size_t)qa*96 + kq;
    aF[tl][0] = *(const short8*)(qrow);
    aF[tl][1] = *(const short8*)(qrow + 32);
    aF[tl][2] = *(const short8*)(qrow + 64);
  }

  // per-row coords (C-layout rows m = tl*16 + quad*4 + r)
  int yq[2][4], xq[2][4], tq[2][4], livx[2][4], liv[2][4];
  #pragma unroll
  for (int tl = 0; tl < 2; ++tl)
  #pragma unroll
  for (int r = 0; r < 4; ++r){
    int gq = q0 + tl*16 + quad*4 + r;
    liv[tl][r]  = (gq >= 1);
    livx[tl][r] = (gq >= 1 && gq <= 6272);
    int s = (gq >= 1) ? gq - 1 : 0;
    tq[tl][r] = s / 784; int r2 = s - tq[tl][r]*784; yq[tl][r] = r2 / 28; xq[tl][r] = r2 - yq[tl][r]*28;
  }

  // ---- shared rel GEMM: wave wv computes col tiles wv*2, wv*2+1 for BOTH row tiles --
  #pragma unroll
  for (int j = 0; j < 2; ++j){
    const int c = (wv*2 + j)*16 + col;
    const unsigned short* rrow;
    if (c < 55)       rrow = rph + (size_t)c*96;
    else if (c < 110) rrow = rpw + (size_t)(c-55)*96;
    else { int ci = c-110; if (ci > 14) ci = 14; rrow = rpt + (size_t)ci*96; }
    rrow += kq;
    short8 b0 = *(const short8*)(rrow);
    short8 b1 = *(const short8*)(rrow + 32);
    short8 b2 = *(const short8*)(rrow + 64);
    #pragma unroll
    for (int tl = 0; tl < 2; ++tl){
      floatx4 rc = {0.f,0.f,0.f,0.f};
      rc = __builtin_amdgcn_mfma_f32_16x16x32_bf16(aF[tl][0], b0, rc, 0,0,0);
      rc = __builtin_amdgcn_mfma_f32_16x16x32_bf16(aF[tl][1], b1, rc, 0,0,0);
      rc = __builtin_amdgcn_mfma_f32_16x16x32_bf16(aF[tl][2], b2, rc, 0,0,0);
      #pragma unroll
      for (int r = 0; r < 4; ++r){
        if (!livx[tl][r]) continue;
        const int m = tl*16 + quad*4 + r;
        if (c < 55){
          int u = yq[tl][r] + 24 - c;
          if (u >= 0 && u <= 24 && (u & 3) == 0) rel[(u >> 2)*36 + m] = rc[r];
        } else if (c < 110){
          int u = xq[tl][r] + 24 - (c - 55);
          if (u >= 0 && u <= 24 && (u & 3) == 0) rel[(8 + (u >> 2))*36 + m] = rc[r];
        } else if (c < 125){
          int u = tq[tl][r] + 7 - (c - 110);
          if (u >= 0 && u <= 7) rel[(16 + u)*36 + m] = rc[r];
        }
      }
    }
  }
  __syncthreads();

  // QK^T over 7 literal k-tiles per wave (t clamped to 25; clamp dups are all-pad),
  // each K fragment feeds both q-tiles.
  floatx4 acc[2][7];
  float mx[2][4] = {{-1e30f,-1e30f,-1e30f,-1e30f},{-1e30f,-1e30f,-1e30f,-1e30f}};
  #pragma unroll
  for (int i = 0; i < 7; ++i){
    int t = wv*7 + i; if (t > 25) t = 25;
    const unsigned short* krow = kbase + (size_t)(t*16 + col)*96 + kq;
    short8 b0 = *(const short8*)(krow);
    short8 b1 = *(const short8*)(krow + 32);
    short8 b2 = *(const short8*)(krow + 64);
    const int key = t*16 + col;
    const bool validk = (key < 393);
    int kt = 0, ky = 0, kx = 0;
    if (key >= 1 && validk){
      int ks = key - 1; kt = ks / 49; int krm = ks - kt*49; ky = krm / 7; kx = krm - ky*7;
    }
    floatx4v rh0 = *(const floatx4v*)(rel + ky*36 + quad*4);
    floatx4v rh1 = *(const floatx4v*)(rel + ky*36 + 16 + quad*4);
    floatx4v rw0 = *(const floatx4v*)(rel + (8 + kx)*36 + quad*4);
    floatx4v rw1 = *(const floatx4v*)(rel + (8 + kx)*36 + 16 + quad*4);
    floatx4v rt0 = *(const floatx4v*)(rel + (16 + kt)*36 + quad*4);
    floatx4v rt1 = *(const floatx4v*)(rel + (16 + kt)*36 + 16 + quad*4);
    #pragma unroll
    for (int tl = 0; tl < 2; ++tl){
      floatx4 a = {0.f,0.f,0.f,0.f};
      a = __builtin_amdgcn_mfma_f32_16x16x32_bf16(aF[tl][0], b0, a, 0,0,0);
      a = __builtin_amdgcn_mfma_f32_16x16x32_bf16(aF[tl][1], b1, a, 0,0,0);
      a = __builtin_amdgcn_mfma_f32_16x16x32_bf16(aF[tl][2], b2, a, 0,0,0);
      #pragma unroll
      for (int r = 0; r < 4; ++r){
        float s;
        if (!validk) s = -1e30f;
        else {
          s = a[r] * SCALE_F;
          if (key >= 1 && liv[tl][r]){
            float rhv = tl ? rh1[r] : rh0[r];
            float rwv = tl ? rw1[r] : rw0[r];
            float rtv = tl ? rt1[r] : rt0[r];
            s += rhv + rwv + rtv;
          }
        }
        a[r] = s;
        mx[tl][r] = fmaxf(mx[tl][r], s);
      }
      acc[tl][i] = a;
    }
  }
  #pragma unroll
  for (int tl = 0; tl < 2; ++tl)
  #pragma unroll
  for (int r = 0; r < 4; ++r){
    #pragma unroll
    for (int o = 1; o < 16; o <<= 1) mx[tl][r] = fmaxf(mx[tl][r], __shfl_xor(mx[tl][r], o, 64));
  }
  if (col == 0){
    #pragma unroll
    for (int tl = 0; tl < 2; ++tl)
    #pragma unroll
    for (int r = 0; r < 4; ++r) mx_sh[wv][tl*16 + quad*4 + r] = mx[tl][r];
  }
  __syncthreads();

  float M[2][4];
  #pragma unroll
  for (int tl = 0; tl < 2; ++tl)
  #pragma unroll
  for (int r = 0; r < 4; ++r){
    const int m = tl*16 + quad*4 + r;
    float m01 = fmaxf(mx_sh[0][m], mx_sh[1][m]);
    float m23 = fmaxf(mx_sh[2][m], mx_sh[3][m]);
    M[tl][r] = fmaxf(m01, m23);
  }
  float sum[2][4] = {{0.f,0.f,0.f,0.f},{0.f,0.f,0.f,0.f}};
  #pragma unroll
  for (int i = 0; i < 7; ++i){
    #pragma unroll
    for (int tl = 0; tl < 2; ++tl)
    #pragma unroll
    for (int r = 0; r < 4; ++r){
      float e = __expf(acc[tl][i][r] - M[tl][r]);
      acc[tl][i][r] = e; sum[tl][r] += e;
    }
  }
  #pragma unroll
  for (int tl = 0; tl < 2; ++tl)
  #pragma unroll
  for (int r = 0; r < 4; ++r){
    #pragma unroll
    for (int o = 1; o < 16; o <<= 1) sum[tl][r] += __shfl_xor(sum[tl][r], o, 64);
  }
  if (col == 0){
    #pragma unroll
    for (int tl = 0; tl < 2; ++tl)
    #pragma unroll
    for (int r = 0; r < 4; ++r) sum_sh[wv][tl*16 + quad*4 + r] = sum[tl][r];
  }
  #pragma unroll
  for (int i = 0; i < 7; ++i){
    int t = wv*7 + i; if (t > 25) t = 25;
    #pragma unroll
    for (int tl = 0; tl < 2; ++tl)
    #pragma unroll
    for (int r = 0; r < 4; ++r)
      P[(tl*16 + quad*4 + r)*PSTR + t*16 + col] = f2b(acc[tl][i][r]);
  }
  __syncthreads();

  // PV: 12 (tile,slot) pairs over 4 waves = 3 each; waves 0,1 -> tile A, 2,3 -> tile B
  const int tlw = wv >> 1;
  float linv4[4];
  #pragma unroll
  for (int r = 0; r < 4; ++r){
    const int m = tlw*16 + quad*4 + r;
    linv4[r] = 1.f / (sum_sh[0][m] + sum_sh[1][m] + sum_sh[2][m] + sum_sh[3][m]);
  }

  short8 pf[13];
  #pragma unroll
  for (int s = 0; s < 13; ++s)
    pf[s] = *(const short8*)(P + (tlw*16 + col)*PSTR + s*32 + kq);

  #pragma unroll
  for (int j = 0; j < 3; ++j){
    const int slot = (wv & 1)*3 + j;
    const int dd = slot*16 + col;
    const unsigned short* vrow = vbase + (size_t)dd*416 + kq;
    floatx4 o = {0.f,0.f,0.f,0.f};
    #pragma unroll
    for (int s = 0; s < 13; ++s){
      short8 vf = *(const short8*)(vrow + s*32);
      o = __builtin_amdgcn_mfma_f32_16x16x32_bf16(pf[s], vf, o, 0,0,0);
    }
    #pragma unroll
    for (int r = 0; r < 4; ++r){
      int gq = q0 + tlw*16 + quad*4 + r;
      if (gq <= 6272){
        float val = o[r] * linv4[r] + b2f(qbase[(size_t)gq*96 + dd]);
        ao[((size_t)bb*6273 + gq)*192 + head*96 + dd] = f2b(val);
      }
    }
  }
}

// ---------------- K5: proj GEMM v2 — 32 rows/block, full 192 cols, LDS-coalesced ----
// ao read ONCE (was 3x via col-block replicas); output written via float4 (flag=1)
// or 8B-bf16 (flag=0) coalesced stores from a 24.5KB fp32 LDS tile (was 4B scalar).
__global__ __launch_bounds__(256) void k_proj(
    const unsigned short* __restrict__ ao, const unsigned short* __restrict__ w,
    const unsigned short* __restrict__ bias, void* __restrict__ out, const int* __restrict__ flagp)
{
  __shared__ __align__(16) float Tf[32*196];   // 24.5 KB
  const int flag = *flagp;
  const int tid = threadIdx.x;
  const int lane = tid & 63;
  const int wv = tid >> 6;
  const int quad = lane >> 4;
  const int col_l = lane & 15;
  const int kq = quad * 8;

  const int m_base = blockIdx.x * 32;
  const int tl = wv >> 1;                      // row tile 0/1
  const int ch = wv & 1;                       // col half 0/1

  int ma = m_base + tl*16 + col_l; if (ma > 25091) ma = 25091;
  const unsigned short* arow = ao + (size_t)ma*192 + kq;
  short8 af[6];
  #pragma unroll
  for (int s = 0; s < 6; ++s) af[s] = *(const short8*)(arow + 32*s);

  #pragma unroll
  for (int ct = 0; ct < 6; ++ct){
    const int col = ch*96 + ct*16 + col_l;
    const unsigned short* wrow = w + col*192 + kq;
    floatx4 acc = {0.f,0.f,0.f,0.f};
    #pragma unroll
    for (int s = 0; s < 6; ++s){
      short8 b = *(const short8*)(wrow + 32*s);
      acc = __builtin_amdgcn_mfma_f32_16x16x32_bf16(af[s], b, acc, 0,0,0);
    }
    float bv = b2f(bias[col]);
    #pragma unroll
    for (int r = 0; r < 4; ++r)
      Tf[(tl*16 + quad*4 + r)*196 + col] = acc[r] + bv;
  }
  __syncthreads();

  // coalesced write-out: 32 rows x 48 float4 = 1536 chunks, 6 per thread
  #pragma unroll
  for (int k = 0; k < 6; ++k){
    int c = tid + k*256;
    int row = c / 48;
    int off = c - row*48;
    int m = m_base + row;
    if (m < 25092){
      floatx4v v = *(const floatx4v*)(Tf + row*196 + off*4);
      if (flag){
        *(floatx4v*)((float*)out + (size_t)m*192 + off*4) = v;
      } else {
        short4v o;
        #pragma unroll
        for (int j = 0; j < 4; ++j) o[j] = (short)f2b(v[j]);
        *(short4v*)((unsigned short*)out + (size_t)m*192 + off*4) = o;
      }
    }
  }
}

extern "C" void kernel_launch(void* const* d_in, const int* in_sizes, int n_in,
                              void* d_out, int out_size, void* d_ws, size_t ws_size,
                              hipStream_t stream)
{
  char* p = (char*)d_ws;
  int* flagp = (int*)p; p += 16;
  unsigned short* conv = (unsigned short*)p;

  ConvDesc desc;
  long long cum = 0;
  for (int i = 0; i < 17; ++i){
    desc.src[i] = d_in[i];
    desc.off[i] = cum;
    desc.count[i] = in_sizes[i];
    cum += in_sizes[i];
  }
  p += (size_t)cum * 2;

  unsigned short* q_raw  = (unsigned short*)p; p += (size_t)19268352*2;
  unsigned short* kc     = (unsigned short*)p; p += (size_t)2457600*2;
  unsigned short* vc     = (unsigned short*)p; p += (size_t)2457600*2;
  unsigned short* kcls   = (unsigned short*)p; p += (size_t)768*2;
  unsigned short* vcls   = (unsigned short*)p; p += (size_t)768*2;
  unsigned short* q_pool = (unsigned short*)p; p += (size_t)4817664*2;
  unsigned short* kp_buf = (unsigned short*)p; p += (size_t)319488*2;
  unsigned short* v_t    = (unsigned short*)p; p += (size_t)319488*2;
  unsigned short* a_out  = q_raw;   // q_raw dead after k_pool

  const unsigned short* cqkv_w = conv + desc.off[1];
  const unsigned short* cqkv_b = conv + desc.off[2];
  const unsigned short* cproj_w= conv + desc.off[3];
  const unsigned short* cproj_b= conv + desc.off[4];
  const unsigned short* cpq_w  = conv + desc.off[5];
  const unsigned short* cnq_g  = conv + desc.off[6];
  const unsigned short* cnq_b  = conv + desc.off[7];
  const unsigned short* cpk_w  = conv + desc.off[8];
  const unsigned short* cnk_g  = conv + desc.off[9];
  const unsigned short* cnk_b  = conv + desc.off[10];
  const unsigned short* cpv_w  = conv + desc.off[11];
  const unsigned short* cnv_g  = conv + desc.off[12];
  const unsigned short* cnv_b  = conv + desc.off[13];
  const unsigned short* crph   = conv + desc.off[14];
  const unsigned short* crpw   = conv + desc.off[15];
  const unsigned short* crpt   = conv + desc.off[16];

  k_convert<<<dim3(16, 16), 256, 0, stream>>>(desc, conv, flagp, (const unsigned int*)d_in[0]);
  k_qkv  <<<dim3(1971), 256, 0, stream>>>(d_in[0], cqkv_w, cqkv_b, q_raw, kc, vc, kcls, vcls, flagp);
  k_pool <<<dim3(3115), 384, 0, stream>>>(q_raw, cpq_w, cnq_g, cnq_b, q_pool,
                                          kc, vc, kcls, vcls,
                                          cpk_w, cnk_g, cnk_b, cpv_w, cnv_g, cnv_b, kp_buf, v_t);
  k_attn <<<dim3(197, 8), 256, 0, stream>>>(q_pool, kp_buf, v_t, crph, crpw, crpt, a_out, 0);
  k_proj <<<dim3(785), 256, 0, stream>>>(a_out, cproj_w, cproj_b, d_out, flagp);
}

// Round 12
// 257.744 us; speedup vs baseline: 1.0254x; 1.0254x over previous
//
#include <hip/hip_runtime.h>
#include <hip/hip_bf16.h>

typedef short short8 __attribute__((ext_vector_type(8)));
typedef float floatx4 __attribute__((ext_vector_type(4)));
typedef float floatx4v __attribute__((ext_vector_type(4)));

#define SCALE_F 0.10206207261596575f

static __device__ __forceinline__ float b2f(unsigned short u){
  unsigned int v = ((unsigned int)u) << 16; float f;
  __builtin_memcpy(&f, &v, 4); return f;
}
static __device__ __forceinline__ unsigned short f2b(float f){
  __hip_bfloat16 h = __float2bfloat16(f);
  unsigned short u; __builtin_memcpy(&u, &h, 2); return u;
}
static __device__ __forceinline__ int map20(int i){
  return (i < 2) ? i : 7 + ((i-2)/3)*8 + ((i-2)%3);
}

struct ConvDesc {
  const void* src[17];
  long long off[17];
  int count[17];
};

// ---------------- K0: dtype detect + convert SMALL tensors (1..16) to bf16 ------------
__global__ __launch_bounds__(256) void k_convert(ConvDesc d, unsigned short* dst_base,
                                                 int* flagp, const unsigned int* xprobe)
{
  __shared__ int sflag;
  if (threadIdx.x < 64){
    unsigned int w = xprobe[1024 + threadIdx.x];
    int e = (w >> 7) & 0xFF;
    int pl = (e >= 90 && e <= 140) ? 1 : 0;
    unsigned long long m = __ballot(pl);
    if (threadIdx.x == 0){
      sflag = (__popcll(m) < 40) ? 1 : 0;   // 1 = inputs are fp32
      if (blockIdx.x == 0 && blockIdx.y == 0) *flagp = sflag;
    }
  }
  __syncthreads();
  const int flag = sflag;
  const int t = blockIdx.y + 1;             // skip x (tensor 0)
  const int cnt = d.count[t];
  unsigned short* dst = dst_base + d.off[t];
  const float* sf = (const float*)d.src[t];
  const unsigned short* su = (const unsigned short*)d.src[t];
  for (int i = blockIdx.x*blockDim.x + threadIdx.x; i < cnt; i += gridDim.x*blockDim.x){
    dst[i] = flag ? f2b(sf[i]) : su[i];
  }
}

// load one 16-row A-fragment triple from x (flag-dependent dtype)
static __device__ __forceinline__ void load_x_frag(
    const void* xr_, int flag, size_t elem_off, short8& a0, short8& a1, short8& a2)
{
  if (flag){
    const float* xr = (const float*)xr_ + elem_off;
    floatx4v f0 = *(const floatx4v*)(xr),      f1 = *(const floatx4v*)(xr+4);
    floatx4v f2 = *(const floatx4v*)(xr+32),   f3 = *(const floatx4v*)(xr+36);
    floatx4v f4 = *(const floatx4v*)(xr+64),   f5 = *(const floatx4v*)(xr+68);
    #pragma unroll
    for (int j = 0; j < 4; ++j){
      a0[j] = (short)f2b(f0[j]); a0[j+4] = (short)f2b(f1[j]);
      a1[j] = (short)f2b(f2[j]); a1[j+4] = (short)f2b(f3[j]);
      a2[j] = (short)f2b(f4[j]); a2[j+4] = (short)f2b(f5[j]);
    }
  } else {
    const unsigned short* xr = (const unsigned short*)xr_ + elem_off;
    a0 = *(const short8*)(xr);
    a1 = *(const short8*)(xr + 32);
    a2 = *(const short8*)(xr + 64);
  }
}

// ---------------- K1: merged QKV GEMM ----------------
// Q path writes q_raw in [bh][token][96] layout via an LDS transpose tile.
__global__ __launch_bounds__(256) void k_qkv(
    const void* __restrict__ x, const unsigned short* __restrict__ w,
    const unsigned short* __restrict__ bias, unsigned short* __restrict__ qr,
    unsigned short* __restrict__ kc, unsigned short* __restrict__ vc,
    unsigned short* __restrict__ kcls, unsigned short* __restrict__ vcls,
    const int* __restrict__ flagp)
{
  __shared__ __align__(16) unsigned short T[64*200];   // 25.6 KB (Q path only)
  const int flag = *flagp;
  const int tid = threadIdx.x;
  const int lane = tid & 63;
  const int wv = tid >> 6;
  const int kq = (lane >> 4) * 8;
  const int quad = lane >> 4;
  const int col_l = lane & 15;

  if (blockIdx.x < 1569){
    // ---- Q path ----
    const int m_base = blockIdx.x * 64;
    const int row_l = wv * 16;
    int ma = m_base + row_l + col_l; if (ma > 100355) ma = 100355;
    short8 a0, a1, a2;
    load_x_frag(x, flag, (size_t)ma*96 + kq, a0, a1, a2);

    #pragma unroll
    for (int ct = 0; ct < 12; ++ct){
      int col = ct*16 + col_l;
      const unsigned short* wrow = w + col*96 + kq;
      short8 b0 = *(const short8*)(wrow);
      short8 b1 = *(const short8*)(wrow + 32);
      short8 b2 = *(const short8*)(wrow + 64);
      float bv = b2f(bias[col]);
      floatx4 acc = {0.f,0.f,0.f,0.f};
      acc = __builtin_amdgcn_mfma_f32_16x16x32_bf16(a0, b0, acc, 0,0,0);
      acc = __builtin_amdgcn_mfma_f32_16x16x32_bf16(a1, b1, acc, 0,0,0);
      acc = __builtin_amdgcn_mfma_f32_16x16x32_bf16(a2, b2, acc, 0,0,0);
      #pragma unroll
      for (int r = 0; r < 4; ++r)
        T[(row_l + quad*4 + r)*200 + ct*16 + col_l] = f2b(acc[r] + bv);
    }
    __syncthreads();

    // coalesced write-out: 1536 short8 chunks, 6 per thread
    #pragma unroll
    for (int k = 0; k < 6; ++k){
      int c = tid + k*256;
      int row = c / 24;
      int off = c - row*24;
      int m = m_base + row;
      if (m < 100356){
        int bb2 = m / 25089;
        int ntok = m - bb2*25089;
        int col8 = off*8;                  // 0..184
        int head = (col8 >= 96) ? 1 : 0;
        int d = col8 - head*96;
        short8 v = *(const short8*)(T + row*200 + col8);
        *(short8*)(qr + ((size_t)(bb2*2 + head)*25089 + (size_t)ntok)*96 + d) = v;
      }
    }
  } else {
    // ---- KV path (unchanged) ----
    const int id = blockIdx.x - 1569;
    const int isv = id / 201;
    const int bx = id - isv*201;
    const int rbase = bx * 64 + wv * 16;

    int rhoA = rbase + col_l; if (rhoA > 12803) rhoA = 12803;
    int bA, nA;
    if (rhoA < 4){ bA = rhoA; nA = 0; }
    else {
      int rp = rhoA - 4;
      bA = rp / 3200; int rem = rp - bA*3200;
      int t = rem / 400; int s = rem - t*400;
      int ry = s / 20, rx = s - ry*20;
      nA = 1 + (t*56 + map20(ry))*56 + map20(rx);
    }
    short8 a0, a1, a2;
    load_x_frag(x, flag, ((size_t)bA*25089 + nA)*96 + kq, a0, a1, a2);

    int isCls[4], bI[4], baseI[4], valid[4];
    #pragma unroll
    for (int r = 0; r < 4; ++r){
      int rho = rbase + quad*4 + r;
      valid[r] = (rho < 12804);
      if (rho > 12803) rho = 12803;
      if (rho < 4){ isCls[r] = 1; bI[r] = rho; baseI[r] = 0; }
      else {
        int rp = rho - 4;
        int b = rp / 3200; int rem = rp - b*3200;
        int t = rem / 400; int s = rem - t*400;
        int ry = s / 20, rx = s - ry*20;
        isCls[r] = 0; bI[r] = b;
        baseI[r] = (((b*8 + t)*20 + ry)*20 + rx)*192;
      }
    }

    unsigned short* buf  = isv ? vc : kc;
    unsigned short* bufc = isv ? vcls : kcls;
    #pragma unroll
    for (int ct = 0; ct < 12; ++ct){
      const int col = 192 + (isv*12 + ct)*16 + col_l;
      const unsigned short* wrow = w + col*96 + kq;
      short8 b0 = *(const short8*)(wrow);
      short8 b1 = *(const short8*)(wrow + 32);
      short8 b2 = *(const short8*)(wrow + 64);
      float bv = b2f(bias[col]);
      floatx4 acc = {0.f,0.f,0.f,0.f};
      acc = __builtin_amdgcn_mfma_f32_16x16x32_bf16(a0, b0, acc, 0,0,0);
      acc = __builtin_amdgcn_mfma_f32_16x16x32_bf16(a1, b1, acc, 0,0,0);
      acc = __builtin_amdgcn_mfma_f32_16x16x32_bf16(a2, b2, acc, 0,0,0);
      const int head = ct / 6;
      const int dstat = (ct % 6) * 16;
      #pragma unroll
      for (int r = 0; r < 4; ++r){
        if (valid[r]){
          float o = acc[r] + bv;
          if (isCls[r]) bufc[(bI[r]*2 + head)*96 + dstat + col_l] = f2b(o);
          else          buf[baseI[r] + head*96 + dstat + col_l]   = f2b(o);
        }
      }
    }
  }
}

// ---------------- K2: merged pooling ------------------------------------------------
// Q-pool path: blocks 0..895, each computes TWO t-outputs (t=2g, 2g+1) so the 4
// needed t-slices replace the 6 of two separate blocks (1.5x read cut). Bijective
// XCD swizzle (rb%8)*112+rb/8 gives each XCD one bh's q_raw slice (L2-resident).
// KV-pool path: blocks 896.. (unchanged logic).
__global__ __launch_bounds__(384) void k_pool(
    const unsigned short* __restrict__ qr, const unsigned short* __restrict__ cwq,
    const unsigned short* __restrict__ gq, const unsigned short* __restrict__ btaq,
    unsigned short* __restrict__ qp,
    const unsigned short* __restrict__ kc, const unsigned short* __restrict__ vc,
    const unsigned short* __restrict__ kcls, const unsigned short* __restrict__ vcls,
    const unsigned short* __restrict__ cwk, const unsigned short* __restrict__ gk, const unsigned short* __restrict__ bk,
    const unsigned short* __restrict__ cwv, const unsigned short* __restrict__ gv, const unsigned short* __restrict__ bv,
    unsigned short* __restrict__ kp, unsigned short* __restrict__ vt)
{
  const int tid = threadIdx.x;
  if (blockIdx.x < 896){
    // ================= Q-pool path (t-paired) =================
    __shared__ float wlds[27*96];
    __shared__ float gls[96], bls[96];
    __shared__ float ls1[2][29*12], ls2[2][29*12];
    __shared__ float lmean[2][29], linvs[2][29];

    const int rb = blockIdx.x;
    const int lbid = (rb & 7)*112 + (rb >> 3);   // XCD-affinity swizzle (bijective)
    const int y   = lbid % 28;
    const int grp = lbid / 28;                   // 0..31
    const int bh  = grp >> 2;
    const int g   = grp & 3;
    const int t0  = g*2;
    const bool has_cls = (y == 0 && g == 0);

    for (int idx = tid; idx < 27*96; idx += 384){
      int tap = idx / 96, d = idx - tap*96;
      wlds[idx] = b2f(cwq[d*27 + tap]);
    }
    for (int idx = tid; idx < 96; idx += 384){
      gls[idx] = b2f(gq[idx]); bls[idx] = b2f(btaq[idx]);
    }
    __syncthreads();

    const int x = tid / 12, dg = tid - x*12;
    const unsigned short* qbh = qr + (size_t)bh*25089*96;
    float val[2][8] = {{0,0,0,0,0,0,0,0},{0,0,0,0,0,0,0,0}};

    if (x < 28){
      #pragma unroll
      for (int tt4 = 0; tt4 < 4; ++tt4){
        const int tt = t0 - 1 + tt4;
        if (tt < 0 || tt >= 8) continue;
        #pragma unroll
        for (int dy = 0; dy < 3; ++dy){
          int yy = 2*y + dy - 1; if (yy < 0 || yy >= 56) continue;
          #pragma unroll
          for (int dx = 0; dx < 3; ++dx){
            int xv = 2*x + dx - 1; if (xv < 0 || xv >= 56) continue;
            short8 v = *(const short8*)(qbh + (size_t)(1 + (tt*56 + yy)*56 + xv)*96 + dg*8);
            float fv[8];
            #pragma unroll
            for (int j = 0; j < 8; ++j) fv[j] = b2f((unsigned short)v[j]);
            if (tt4 < 3){                      // tap dt = tt4 for output t0
              const float* wr = wlds + ((tt4*3+dy)*3+dx)*96 + dg*8;
              #pragma unroll
              for (int j = 0; j < 8; ++j) val[0][j] += fv[j] * wr[j];
            }
            if (tt4 >= 1){                     // tap dt = tt4-1 for output t0+1
              const float* wr = wlds + (((tt4-1)*3+dy)*3+dx)*96 + dg*8;
              #pragma unroll
              for (int j = 0; j < 8; ++j) val[1][j] += fv[j] * wr[j];
            }
          }
        }
      }
      #pragma unroll
      for (int tp = 0; tp < 2; ++tp){
        float s1 = 0.f, s2 = 0.f;
        #pragma unroll
        for (int j = 0; j < 8; ++j){ s1 += val[tp][j]; s2 += val[tp][j]*val[tp][j]; }
        ls1[tp][x*12+dg] = s1; ls2[tp][x*12+dg] = s2;
      }
    } else if (has_cls && tid >= 348 && tid < 360){
      int cdg = tid - 348;
      short8 v = *(const short8*)(qbh + cdg*8);
      float s1 = 0.f, s2 = 0.f;
      #pragma unroll
      for (int j = 0; j < 8; ++j){ val[0][j] = b2f((unsigned short)v[j]); s1 += val[0][j]; s2 += val[0][j]*val[0][j]; }
      ls1[0][28*12+cdg] = s1; ls2[0][28*12+cdg] = s2;
    }
    __syncthreads();

    if (tid < 58){
      int tp = tid / 29, row = tid - tp*29;
      if (row < 28 || (row == 28 && tp == 0 && has_cls)){
        float s1 = 0.f, s2 = 0.f;
        #pragma unroll
        for (int k = 0; k < 12; ++k){ s1 += ls1[tp][row*12+k]; s2 += ls2[tp][row*12+k]; }
        float mean = s1 * (1.f/96.f);
        float var  = s2 * (1.f/96.f) - mean*mean;
        lmean[tp][row] = mean; linvs[tp][row] = rsqrtf(var + 1e-5f);
      }
    }
    __syncthreads();

    if (x < 28){
      #pragma unroll
      for (int tp = 0; tp < 2; ++tp){
        float mean = lmean[tp][x], inv = linvs[tp][x];
        int tok = 1 + ((t0 + tp)*28 + y)*28 + x;
        short8 o;
        #pragma unroll
        for (int j = 0; j < 8; ++j)
          o[j] = (short)f2b((val[tp][j] - mean)*inv*gls[dg*8+j] + bls[dg*8+j]);
        *(short8*)(qp + ((size_t)bh*6273 + tok)*96 + dg*8) = o;
      }
    } else if (has_cls && tid >= 348 && tid < 360){
      int cdg = tid - 348;
      float mean = lmean[0][28], inv = linvs[0][28];
      short8 o;
      #pragma unroll
      for (int j = 0; j < 8; ++j)
        o[j] = (short)f2b((val[0][j] - mean)*inv*gls[cdg*8+j] + bls[cdg*8+j]);
      *(short8*)(qp + (size_t)bh*6273*96 + cdg*8) = o;
    }
  } else {
    // ================= KV-pool path: 3 units of 128 threads =================
    __shared__ float r1[3][128], r2s[3][128];
    const int unit = tid >> 7;              // 0..2
    const int d = tid & 127;
    const int u = (blockIdx.x - 896)*3 + unit;
    const bool live = (u < 6656);
    int isv = 0, bh = 0, key = 0;
    if (live){
      isv = u / 3328; int rem = u - isv*3328;
      bh = rem / 416; key = rem - bh*416;
    }
    const bool pad = (key >= 393);
    const int b = bh >> 1, head = bh & 1;
    const unsigned short* buf  = isv ? vc : kc;
    const unsigned short* bufc = isv ? vcls : kcls;
    const unsigned short* cw = (isv == 0) ? cwk : cwv;
    const unsigned short* g  = (isv == 0) ? gk : gv;
    const unsigned short* bt = (isv == 0) ? bk : bv;

    float val = 0.f;
    if (live && !pad && d < 96){
      if (key == 0) val = b2f(bufc[bh*96 + d]);
      else {
        int s = key - 1; int t = s / 49; int r2 = s - t*49; int y = r2 / 7; int xx = r2 - y*7;
        const unsigned short* wr = cw + d*27;
        float sum = 0.f;
        #pragma unroll
        for (int dt = 0; dt < 3; ++dt){
          int tt = t + dt - 1; if (tt < 0 || tt >= 8) continue;
          #pragma unroll
          for (int dy = 0; dy < 3; ++dy){
            if (y == 0 && dy == 0) continue;
            int ry = (y == 0) ? (dy - 1) : 2 + 3*(y-1) + dy;
            #pragma unroll
            for (int dx = 0; dx < 3; ++dx){
              if (xx == 0 && dx == 0) continue;
              int rx = (xx == 0) ? (dx - 1) : 2 + 3*(xx-1) + dx;
              sum += b2f(buf[(((b*8 + tt)*20 + ry)*20 + rx)*192 + head*96 + d]) * b2f(wr[(dt*3+dy)*3+dx]);
            }
          }
        }
        val = sum;
      }
    }
    r1[unit][d]  = (d < 96) ? val : 0.f;
    r2s[unit][d] = (d < 96) ? val*val : 0.f;
    __syncthreads();
    for (int off = 64; off > 0; off >>= 1){
      if (d < off){ r1[unit][d] += r1[unit][d+off]; r2s[unit][d] += r2s[unit][d+off]; }
      __syncthreads();
    }
    if (live && d < 96){
      float mean = r1[unit][0] * (1.f/96.f);
      float var  = r2s[unit][0] * (1.f/96.f) - mean*mean;
      float inv = rsqrtf(var + 1e-5f);
      float o = pad ? 0.f : (val - mean)*inv*b2f(g[d]) + b2f(bt[d]);
      if (isv == 0) kp[((size_t)bh*416 + key)*96 + d] = f2b(o);
      else          vt[((size_t)bh*96 + d)*416 + key] = f2b(o);
    }
  }
}

// ---------------- K4: fused attention — 32 q rows/block (R2 proven version) ---------
#define PSTR 424
__global__ __launch_bounds__(256, 3) void k_attn(
    const unsigned short* __restrict__ qp, const unsigned short* __restrict__ kp,
    const unsigned short* __restrict__ vt,
    const unsigned short* __restrict__ rph, const unsigned short* __restrict__ rpw,
    const unsigned short* __restrict__ rpt,
    unsigned short* __restrict__ ao, const int q_off)
{
  __shared__ unsigned short P[32*PSTR];              // 27.1 KB
  __shared__ __align__(16) float rel[24*36 + 4];     // 3.5 KB, [slot][m], stride 36
  __shared__ float mx_sh[4][32], sum_sh[4][32];

  const int bh = blockIdx.y;
  const int bb = bh >> 1, head = bh & 1;
  const int tid = threadIdx.x;
  const int lane = tid & 63;
  const int wv = tid >> 6;                   // 0..3
  const int q0 = (q_off + blockIdx.x) * 32;

  const unsigned short* qbase = qp + (size_t)bh*6273*96;
  const unsigned short* kbase = kp + (size_t)bh*416*96;
  const unsigned short* vbase = vt + (size_t)bh*96*416;

  const int col = lane & 15;
  const int quad = lane >> 4;
  const int kq = quad * 8;

  // Q A-fragments for tile A (rows q0..+15) and tile B (rows q0+16..+31)
  short8 aF[2][3];
  #pragma unroll
  for (int tl = 0; tl < 2; ++tl){
    int qa = q0 + tl*16 + col; if (qa > 6272) qa = 6272;
    const unsigned short* qrow = qbase + (size_t)qa*96 + kq;
    aF[tl][0] = *(const short8*)(qrow);
    aF[tl][1] = *(const short8*)(qrow + 32);
    aF[tl][2] = *(const short8*)(qrow + 64);
  }

  // per-row coords (C-layout rows m = tl*16 + quad*4 + r)
  int yq[2][4], xq[2][4], tq[2][4], livx[2][4], liv[2][4];
  #pragma unroll
  for (int tl = 0; tl < 2; ++tl)
  #pragma unroll
  for (int r = 0; r < 4; ++r){
    int gq = q0 + tl*16 + quad*4 + r;
    liv[tl][r]  = (gq >= 1);
    livx[tl][r] = (gq >= 1 && gq <= 6272);
    int s = (gq >= 1) ? gq - 1 : 0;
    tq[tl][r] = s / 784; int r2 = s - tq[tl][r]*784; yq[tl][r] = r2 / 28; xq[tl][r] = r2 - yq[tl][r]*28;
  }

  // ---- shared rel GEMM: wave wv computes col tiles wv*2, wv*2+1 for BOTH row tiles --
  #pragma unroll
  for (int j = 0; j < 2; ++j){
    const int c = (wv*2 + j)*16 + col;
    const unsigned short* rrow;
    if (c < 55)       rrow = rph + (size_t)c*96;
    else if (c < 110) rrow = rpw + (size_t)(c-55)*96;
    else { int ci = c-110; if (ci > 14) ci = 14; rrow = rpt + (size_t)ci*96; }
    rrow += kq;
    short8 b0 = *(const short8*)(rrow);
    short8 b1 = *(const short8*)(rrow + 32);
    short8 b2 = *(const short8*)(rrow + 64);
    #pragma unroll
    for (int tl = 0; tl < 2; ++tl){
      floatx4 rc = {0.f,0.f,0.f,0.f};
      rc = __builtin_amdgcn_mfma_f32_16x16x32_bf16(aF[tl][0], b0, rc, 0,0,0);
      rc = __builtin_amdgcn_mfma_f32_16x16x32_bf16(aF[tl][1], b1, rc, 0,0,0);
      rc = __builtin_amdgcn_mfma_f32_16x16x32_bf16(aF[tl][2], b2, rc, 0,0,0);
      #pragma unroll
      for (int r = 0; r < 4; ++r){
        if (!livx[tl][r]) continue;
        const int m = tl*16 + quad*4 + r;
        if (c < 55){
          int u = yq[tl][r] + 24 - c;
          if (u >= 0 && u <= 24 && (u & 3) == 0) rel[(u >> 2)*36 + m] = rc[r];
        } else if (c < 110){
          int u = xq[tl][r] + 24 - (c - 55);
          if (u >= 0 && u <= 24 && (u & 3) == 0) rel[(8 + (u >> 2))*36 + m] = rc[r];
        } else if (c < 125){
          int u = tq[tl][r] + 7 - (c - 110);
          if (u >= 0 && u <= 7) rel[(16 + u)*36 + m] = rc[r];
        }
      }
    }
  }
  __syncthreads();

  // QK^T over 7 literal k-tiles per wave (t clamped to 25; clamp dups are all-pad),
  // each K fragment feeds both q-tiles.
  floatx4 acc[2][7];
  float mx[2][4] = {{-1e30f,-1e30f,-1e30f,-1e30f},{-1e30f,-1e30f,-1e30f,-1e30f}};
  #pragma unroll
  for (int i = 0; i < 7; ++i){
    int t = wv*7 + i; if (t > 25) t = 25;
    const unsigned short* krow = kbase + (size_t)(t*16 + col)*96 + kq;
    short8 b0 = *(const short8*)(krow);
    short8 b1 = *(const short8*)(krow + 32);
    short8 b2 = *(const short8*)(krow + 64);
    const int key = t*16 + col;
    const bool validk = (key < 393);
    int kt = 0, ky = 0, kx = 0;
    if (key >= 1 && validk){
      int ks = key - 1; kt = ks / 49; int krm = ks - kt*49; ky = krm / 7; kx = krm - ky*7;
    }
    floatx4v rh0 = *(const floatx4v*)(rel + ky*36 + quad*4);
    floatx4v rh1 = *(const floatx4v*)(rel + ky*36 + 16 + quad*4);
    floatx4v rw0 = *(const floatx4v*)(rel + (8 + kx)*36 + quad*4);
    floatx4v rw1 = *(const floatx4v*)(rel + (8 + kx)*36 + 16 + quad*4);
    floatx4v rt0 = *(const floatx4v*)(rel + (16 + kt)*36 + quad*4);
    floatx4v rt1 = *(const floatx4v*)(rel + (16 + kt)*36 + 16 + quad*4);
    #pragma unroll
    for (int tl = 0; tl < 2; ++tl){
      floatx4 a = {0.f,0.f,0.f,0.f};
      a = __builtin_amdgcn_mfma_f32_16x16x32_bf16(aF[tl][0], b0, a, 0,0,0);
      a = __builtin_amdgcn_mfma_f32_16x16x32_bf16(aF[tl][1], b1, a, 0,0,0);
      a = __builtin_amdgcn_mfma_f32_16x16x32_bf16(aF[tl][2], b2, a, 0,0,0);
      #pragma unroll
      for (int r = 0; r < 4; ++r){
        float s;
        if (!validk) s = -1e30f;
        else {
          s = a[r] * SCALE_F;
          if (key >= 1 && liv[tl][r]){
            float rhv = tl ? rh1[r] : rh0[r];
            float rwv = tl ? rw1[r] : rw0[r];
            float rtv = tl ? rt1[r] : rt0[r];
            s += rhv + rwv + rtv;
          }
        }
        a[r] = s;
        mx[tl][r] = fmaxf(mx[tl][r], s);
      }
      acc[tl][i] = a;
    }
  }
  #pragma unroll
  for (int tl = 0; tl < 2; ++tl)
  #pragma unroll
  for (int r = 0; r < 4; ++r){
    #pragma unroll
    for (int o = 1; o < 16; o <<= 1) mx[tl][r] = fmaxf(mx[tl][r], __shfl_xor(mx[tl][r], o, 64));
  }
  if (col == 0){
    #pragma unroll
    for (int tl = 0; tl < 2; ++tl)
    #pragma unroll
    for (int r = 0; r < 4; ++r) mx_sh[wv][tl*16 + quad*4 + r] = mx[tl][r];
  }
  __syncthreads();

  float M[2][4];
  #pragma unroll
  for (int tl = 0; tl < 2; ++tl)
  #pragma unroll
  for (int r = 0; r < 4; ++r){
    const int m = tl*16 + quad*4 + r;
    float m01 = fmaxf(mx_sh[0][m], mx_sh[1][m]);
    float m23 = fmaxf(mx_sh[2][m], mx_sh[3][m]);
    M[tl][r] = fmaxf(m01, m23);
  }
  float sum[2][4] = {{0.f,0.f,0.f,0.f},{0.f,0.f,0.f,0.f}};
  #pragma unroll
  for (int i = 0; i < 7; ++i){
    #pragma unroll
    for (int tl = 0; tl < 2; ++tl)
    #pragma unroll
    for (int r = 0; r < 4; ++r){
      float e = __expf(acc[tl][i][r] - M[tl][r]);
      acc[tl][i][r] = e; sum[tl][r] += e;
    }
  }
  #pragma unroll
  for (int tl = 0; tl < 2; ++tl)
  #pragma unroll
  for (int r = 0; r < 4; ++r){
    #pragma unroll
    for (int o = 1; o < 16; o <<= 1) sum[tl][r] += __shfl_xor(sum[tl][r], o, 64);
  }
  if (col == 0){
    #pragma unroll
    for (int tl = 0; tl < 2; ++tl)
    #pragma unroll
    for (int r = 0; r < 4; ++r) sum_sh[wv][tl*16 + quad*4 + r] = sum[tl][r];
  }
  #pragma unroll
  for (int i = 0; i < 7; ++i){
    int t = wv*7 + i; if (t > 25) t = 25;
    #pragma unroll
    for (int tl = 0; tl < 2; ++tl)
    #pragma unroll
    for (int r = 0; r < 4; ++r)
      P[(tl*16 + quad*4 + r)*PSTR + t*16 + col] = f2b(acc[tl][i][r]);
  }
  __syncthreads();

  // PV: 12 (tile,slot) pairs over 4 waves = 3 each; waves 0,1 -> tile A, 2,3 -> tile B
  const int tlw = wv >> 1;
  float linv4[4];
  #pragma unroll
  for (int r = 0; r < 4; ++r){
    const int m = tlw*16 + quad*4 + r;
    linv4[r] = 1.f / (sum_sh[0][m] + sum_sh[1][m] + sum_sh[2][m] + sum_sh[3][m]);
  }

  short8 pf[13];
  #pragma unroll
  for (int s = 0; s < 13; ++s)
    pf[s] = *(const short8*)(P + (tlw*16 + col)*PSTR + s*32 + kq);

  #pragma unroll
  for (int j = 0; j < 3; ++j){
    const int slot = (wv & 1)*3 + j;
    const int dd = slot*16 + col;
    const unsigned short* vrow = vbase + (size_t)dd*416 + kq;
    floatx4 o = {0.f,0.f,0.f,0.f};
    #pragma unroll
    for (int s = 0; s < 13; ++s){
      short8 vf = *(const short8*)(vrow + s*32);
      o = __builtin_amdgcn_mfma_f32_16x16x32_bf16(pf[s], vf, o, 0,0,0);
    }
    #pragma unroll
    for (int r = 0; r < 4; ++r){
      int gq = q0 + tlw*16 + quad*4 + r;
      if (gq <= 6272){
        float val = o[r] * linv4[r] + b2f(qbase[(size_t)gq*96 + dd]);
        ao[((size_t)bb*6273 + gq)*192 + head*96 + dd] = f2b(val);
      }
    }
  }
}

// ---------------- K5: proj GEMM (R8 proven version; flag-aware output dtype) --------
__global__ __launch_bounds__(256) void k_proj(
    const unsigned short* __restrict__ ao, const unsigned short* __restrict__ w,
    const unsigned short* __restrict__ bias, void* __restrict__ out, const int* __restrict__ flagp)
{
  const int flag = *flagp;
  const int lane = threadIdx.x & 63;
  const int wv = threadIdx.x >> 6;
  const int c = blockIdx.y*64 + wv*16 + (lane & 15);
  const int kq = (lane >> 4) * 8;
  short8 bfr[6];
  const unsigned short* wrow = w + c*192 + kq;
  #pragma unroll
  for (int s = 0; s < 6; ++s) bfr[s] = *(const short8*)(wrow + 32*s);
  float bv = b2f(bias[c]);
  const int m_base = blockIdx.x * 64;
  for (int i = 0; i < 4; ++i){
    int mt = m_base + i*16;
    int ma = mt + (lane & 15); if (ma > 25091) ma = 25091;
    const unsigned short* arow = ao + (size_t)ma*192 + kq;
    floatx4 acc = {0.f,0.f,0.f,0.f};
    #pragma unroll
    for (int s = 0; s < 6; ++s){
      short8 a = *(const short8*)(arow + 32*s);
      acc = __builtin_amdgcn_mfma_f32_16x16x32_bf16(a, bfr[s], acc, 0,0,0);
    }
    #pragma unroll
    for (int r = 0; r < 4; ++r){
      int m = mt + (lane >> 4)*4 + r;
      if (m < 25092){
        float o = acc[r] + bv;
        if (flag) ((float*)out)[(size_t)m*192 + c] = o;
        else      ((unsigned short*)out)[(size_t)m*192 + c] = f2b(o);
      }
    }
  }
}

extern "C" void kernel_launch(void* const* d_in, const int* in_sizes, int n_in,
                              void* d_out, int out_size, void* d_ws, size_t ws_size,
                              hipStream_t stream)
{
  char* p = (char*)d_ws;
  int* flagp = (int*)p; p += 16;
  unsigned short* conv = (unsigned short*)p;

  ConvDesc desc;
  long long cum = 0;
  for (int i = 0; i < 17; ++i){
    desc.src[i] = d_in[i];
    desc.off[i] = cum;
    desc.count[i] = in_sizes[i];
    cum += in_sizes[i];
  }
  p += (size_t)cum * 2;

  unsigned short* q_raw  = (unsigned short*)p; p += (size_t)19268352*2;
  unsigned short* kc     = (unsigned short*)p; p += (size_t)2457600*2;
  unsigned short* vc     = (unsigned short*)p; p += (size_t)2457600*2;
  unsigned short* kcls   = (unsigned short*)p; p += (size_t)768*2;
  unsigned short* vcls   = (unsigned short*)p; p += (size_t)768*2;
  unsigned short* q_pool = (unsigned short*)p; p += (size_t)4817664*2;
  unsigned short* kp_buf = (unsigned short*)p; p += (size_t)319488*2;
  unsigned short* v_t    = (unsigned short*)p; p += (size_t)319488*2;
  unsigned short* a_out  = q_raw;   // q_raw dead after k_pool

  const unsigned short* cqkv_w = conv + desc.off[1];
  const unsigned short* cqkv_b = conv + desc.off[2];
  const unsigned short* cproj_w= conv + desc.off[3];
  const unsigned short* cproj_b= conv + desc.off[4];
  const unsigned short* cpq_w  = conv + desc.off[5];
  const unsigned short* cnq_g  = conv + desc.off[6];
  const unsigned short* cnq_b  = conv + desc.off[7];
  const unsigned short* cpk_w  = conv + desc.off[8];
  const unsigned short* cnk_g  = conv + desc.off[9];
  const unsigned short* cnk_b  = conv + desc.off[10];
  const unsigned short* cpv_w  = conv + desc.off[11];
  const unsigned short* cnv_g  = conv + desc.off[12];
  const unsigned short* cnv_b  = conv + desc.off[13];
  const unsigned short* crph   = conv + desc.off[14];
  const unsigned short* crpw   = conv + desc.off[15];
  const unsigned short* crpt   = conv + desc.off[16];

  k_convert<<<dim3(16, 16), 256, 0, stream>>>(desc, conv, flagp, (const unsigned int*)d_in[0]);
  k_qkv  <<<dim3(1971), 256, 0, stream>>>(d_in[0], cqkv_w, cqkv_b, q_raw, kc, vc, kcls, vcls, flagp);
  k_pool <<<dim3(3115), 384, 0, stream>>>(q_raw, cpq_w, cnq_g, cnq_b, q_pool,
                                          kc, vc, kcls, vcls,
                                          cpk_w, cnk_g, cnk_b, cpv_w, cnv_g, cnv_b, kp_buf, v_t);
  k_attn <<<dim3(197, 8), 256, 0, stream>>>(q_pool, kp_buf, v_t, crph, crpw, crpt, a_out, 0);
  k_proj <<<dim3(393, 3), 256, 0, stream>>>(a_out, cproj_w, cproj_b, d_out, flagp);
}